// Round 1
// baseline (107.099 us; speedup 1.0000x reference)
//
#include <hip/hip_runtime.h>

typedef short s16x8 __attribute__((ext_vector_type(8)));
typedef __bf16 bf16x8 __attribute__((ext_vector_type(8)));
typedef float f32x4 __attribute__((ext_vector_type(4)));

static __device__ __forceinline__ bf16x8 as_bf(s16x8 v) {
    return __builtin_bit_cast(bf16x8, v);
}

#define BATCH 64
#define CH    64    // input channels C == output channels P == 64
#define HH    56
#define WW    56
#define HW    3136  // 56*56
#define M_TOT 200704 // 64*56*56

static __device__ __forceinline__ ushort sign_bf16(float v) {
    return v > 0.f ? (ushort)0x3F80u : (v < 0.f ? (ushort)0xBF80u : (ushort)0u);
}

// Kernel 1: S[b][h][w][c] = bf16(sign(x[b][c][h][w] + bias0[c]))  (NCHW -> NHWC via LDS)
// Block 0 additionally folds weight signs + BN constants.
__global__ void sign_prep_kernel(const float* __restrict__ x,
                                 const float* __restrict__ bias0,
                                 const float* __restrict__ w,
                                 const float* __restrict__ gamma,
                                 const float* __restrict__ beta,
                                 const float* __restrict__ rmean,
                                 const float* __restrict__ rvar,
                                 const float* __restrict__ bias1,
                                 const float* __restrict__ alpha,
                                 const float* __restrict__ bias2,
                                 ushort* __restrict__ S,
                                 ushort* __restrict__ wsgn,
                                 float* __restrict__ consts) {
    __shared__ ushort tile[64 * 57];
    const int blk = blockIdx.x;          // = b*56 + h
    const int b = blk / HH;
    const int h = blk - b * HH;
    const float* xp = x + (size_t)b * CH * HW + (size_t)h * WW;

    for (int i = threadIdx.x; i < CH * WW; i += blockDim.x) {
        int c = i / WW, ww = i - c * WW;
        float v = xp[(size_t)c * HW + ww] + bias0[c];
        tile[c * 57 + ww] = sign_bf16(v);
    }
    __syncthreads();
    ushort* Sp = S + (size_t)blk * (WW * CH);
    for (int i = threadIdx.x; i < CH * WW; i += blockDim.x) {
        int ww = i >> 6, c = i & 63;
        Sp[i] = tile[c * 57 + ww];
    }

    if (blk == 0) {
        const int t = threadIdx.x;
        if (t < 64) {
            float s = 0.f;
            const float* wp = w + t * 576;
            for (int i = 0; i < 576; ++i) s += fabsf(wp[i]);
            float scale = s * (1.0f / 576.0f);
            float inv = gamma[t] * rsqrtf(rvar[t] + 1e-5f);
            consts[t]       = scale * inv;                      // A_mul
            consts[64 + t]  = beta[t] - rmean[t] * inv + bias1[t]; // B_add
            consts[128 + t] = alpha[t];
            consts[192 + t] = bias2[t];
        }
        // wsgn[tap][p][c] = sign(w[p][c][kh][kw]) as bf16 bits, tap = kh*3+kw
        for (int idx = t; idx < 9 * 64 * 64; idx += blockDim.x) {
            int c = idx & 63, p = (idx >> 6) & 63, tap = idx >> 12;
            float v = w[(((p << 6) + c) * 9) + tap];
            wsgn[idx] = sign_bf16(v);
        }
    }
}

// Kernel 2: implicit-GEMM binary conv + fused BN/residual/PReLU epilogue.
// Block = 256 thr (4 waves). Each wave: 64 positions x 64 channels via
// mfma_f32_16x16x32_bf16 (4 m-tiles x 4 n-tiles x 2 k-steps x 9 taps).
__global__ __launch_bounds__(256, 2)
void conv_kernel(const ushort* __restrict__ S,
                 const ushort* __restrict__ wsgn,
                 const float* __restrict__ x,
                 const float* __restrict__ consts,
                 float* __restrict__ out) {
    __shared__ __align__(16) ushort bsm[9 * 64 * 64]; // 73,728 B

    // Stage all 9 taps of weight signs into LDS with XOR-chunk swizzle:
    // content chunk c8 (8 ch = 16B) stored at chunk (c8 ^ (p&7)).
    for (int i = threadIdx.x; i < 9 * 64 * 8; i += 256) {
        int c8 = i & 7;
        int p = (i >> 3) & 63;
        int tap = i >> 9;
        uint4 v = *(const uint4*)(wsgn + (((tap << 6) + p) << 6) + (c8 << 3));
        *(uint4*)(bsm + (((tap << 6) + p) << 6) + ((c8 ^ (p & 7)) << 3)) = v;
    }
    __syncthreads();

    const int lane = threadIdx.x & 63;
    const int wv = threadIdx.x >> 6;
    const int mbase = (blockIdx.x << 8) + (wv << 6);
    const int lr = lane & 15;   // A-row / D-col index
    const int cg = lane >> 4;   // k-group 0..3

    int bb[4], hb[4], wb[4];
#pragma unroll
    for (int mt = 0; mt < 4; ++mt) {
        int m = mbase + (mt << 4) + lr;
        bb[mt] = m / HW;
        int r = m - bb[mt] * HW;
        hb[mt] = r / WW;
        wb[mt] = r - hb[mt] * WW;
    }

    f32x4 acc[4][4] = {};

#pragma unroll
    for (int tap = 0; tap < 9; ++tap) {
        const int dh = tap / 3 - 1, dw = tap % 3 - 1;
        s16x8 a[4][2];
#pragma unroll
        for (int mt = 0; mt < 4; ++mt) {
            int hh = hb[mt] + dh, ww = wb[mt] + dw;
            bool valid = ((unsigned)hh < (unsigned)HH) & ((unsigned)ww < (unsigned)WW);
            if (valid) {
                const ushort* sp = S + ((((size_t)bb[mt] * HH + hh) * WW + ww) << 6) + (cg << 3);
                a[mt][0] = *(const s16x8*)(sp);
                a[mt][1] = *(const s16x8*)(sp + 32);
            } else {
                a[mt][0] = s16x8{};
                a[mt][1] = s16x8{};
            }
        }
#pragma unroll
        for (int nt = 0; nt < 4; ++nt) {
            const int p = (nt << 4) + lr;
            const ushort* bp = bsm + (((tap << 6) + p) << 6);
            s16x8 b0 = *(const s16x8*)(bp + ((cg ^ (p & 7)) << 3));
            s16x8 b1 = *(const s16x8*)(bp + (((4 + cg) ^ (p & 7)) << 3));
#pragma unroll
            for (int mt = 0; mt < 4; ++mt) {
                acc[mt][nt] = __builtin_amdgcn_mfma_f32_16x16x32_bf16(
                    as_bf(a[mt][0]), as_bf(b0), acc[mt][nt], 0, 0, 0);
                acc[mt][nt] = __builtin_amdgcn_mfma_f32_16x16x32_bf16(
                    as_bf(a[mt][1]), as_bf(b1), acc[mt][nt], 0, 0, 0);
            }
        }
    }

    // Epilogue: out = PReLU(acc*A_mul + B_add + residual) + bias2
#pragma unroll
    for (int mt = 0; mt < 4; ++mt) {
        int m0 = mbase + (mt << 4) + (cg << 2);  // 4 consecutive positions (w-aligned)
        int b = m0 / HW;
        int r = m0 - b * HW;
        int h = r / WW;
        int w0 = r - h * WW;
#pragma unroll
        for (int nt = 0; nt < 4; ++nt) {
            int p = (nt << 4) + lr;
            float am = consts[p];
            float bd = consts[64 + p];
            float al = consts[128 + p];
            float b2 = consts[192 + p];
            size_t off = ((((size_t)b << 6) + p) * HH + h) * WW + w0;
            float4 res = *(const float4*)(x + off);
            float4 o;
            const float* accp = (const float*)&acc[mt][nt];
            const float* rp = (const float*)&res;
            float* op = (float*)&o;
#pragma unroll
            for (int rr = 0; rr < 4; ++rr) {
                float v = accp[rr] * am + bd + rp[rr];
                v = v >= 0.f ? v : al * v;
                op[rr] = v + b2;
            }
            *(float4*)(out + off) = o;
        }
    }
}

extern "C" void kernel_launch(void* const* d_in, const int* in_sizes, int n_in,
                              void* d_out, int out_size, void* d_ws, size_t ws_size,
                              hipStream_t stream) {
    const float* x     = (const float*)d_in[0];
    const float* bias0 = (const float*)d_in[1];
    const float* w     = (const float*)d_in[2];
    const float* gamma = (const float*)d_in[3];
    const float* beta  = (const float*)d_in[4];
    const float* rmean = (const float*)d_in[5];
    const float* rvar  = (const float*)d_in[6];
    const float* bias1 = (const float*)d_in[7];
    const float* alpha = (const float*)d_in[8];
    const float* bias2 = (const float*)d_in[9];
    float* out = (float*)d_out;

    char* ws = (char*)d_ws;
    float* consts = (float*)ws;                       // 256 f32 = 1 KB
    ushort* wsgn  = (ushort*)(ws + 1024);             // 9*64*64*2 = 73,728 B
    ushort* S     = (ushort*)(ws + 1024 + 73728);     // 200704*64*2 = 25,690,112 B

    sign_prep_kernel<<<BATCH * HH, 256, 0, stream>>>(
        x, bias0, w, gamma, beta, rmean, rvar, bias1, alpha, bias2, S, wsgn, consts);

    conv_kernel<<<M_TOT / 256, 256, 0, stream>>>(S, wsgn, x, consts, out);
}

// Round 2
// 75.456 us; speedup vs baseline: 1.4194x; 1.4194x over previous
//
#include <hip/hip_runtime.h>

typedef short s16x8 __attribute__((ext_vector_type(8)));
typedef __bf16 bf16x8 __attribute__((ext_vector_type(8)));
typedef float f32x4 __attribute__((ext_vector_type(4)));
typedef unsigned short ushort4v __attribute__((ext_vector_type(4)));

static __device__ __forceinline__ bf16x8 as_bf(s16x8 v) {
    return __builtin_bit_cast(bf16x8, v);
}

#define BATCH 64
#define CH    64
#define HH    56
#define WW    56
#define HW    3136
#define M_TOT 200704
#define TPAD  60   // LDS tile stride (ushorts): keeps ds_write 8B-aligned

static __device__ __forceinline__ ushort sign_bf16(float v) {
    return v > 0.f ? (ushort)0x3F80u : (v < 0.f ? (ushort)0xBF80u : (ushort)0u);
}

// Kernel 1 (grid = 3584 transpose blocks + 64 weight blocks):
//  blk < 3584:  S[b][h][w][c] = bf16(sign(x[b][c][h][w] + bias0[c]))
//  blk >= 3584: p = blk-3584 -> fold weight signs + BN constants for channel p
__global__ __launch_bounds__(256)
void sign_prep_kernel(const float* __restrict__ x,
                      const float* __restrict__ bias0,
                      const float* __restrict__ w,
                      const float* __restrict__ gamma,
                      const float* __restrict__ beta,
                      const float* __restrict__ rmean,
                      const float* __restrict__ rvar,
                      const float* __restrict__ bias1,
                      const float* __restrict__ alpha,
                      const float* __restrict__ bias2,
                      ushort* __restrict__ S,
                      ushort* __restrict__ wsgn,
                      float* __restrict__ consts) {
    __shared__ ushort tile[64 * TPAD];
    __shared__ float red[4];
    const int tid = threadIdx.x;
    const int blk = blockIdx.x;

    if (blk < BATCH * HH) {
        const int b = blk / HH;
        const int h = blk - b * HH;
        const float* xp = x + (size_t)b * CH * HW + (size_t)h * WW;

        // read: 64 channels x 14 float4 (56 w) each, coalesced 16B
        for (int i = tid; i < CH * 14; i += 256) {
            int c = i / 14, q = i - c * 14;
            float4 v = *(const float4*)(xp + (size_t)c * HW + q * 4);
            float bz = bias0[c];
            ushort4v u;
            u.x = sign_bf16(v.x + bz);
            u.y = sign_bf16(v.y + bz);
            u.z = sign_bf16(v.z + bz);
            u.w = sign_bf16(v.w + bz);
            *(ushort4v*)(tile + c * TPAD + q * 4) = u;  // 8B aligned (c*120+q*8)
        }
        __syncthreads();

        // write: per (w, 8-channel chunk) -> one 16B store, NHWC
        ushort* Sp = S + (size_t)blk * (WW * CH);
        for (int j = tid; j < WW * 8; j += 256) {
            int cb = j & 7, ww = j >> 3;
            s16x8 r;
#pragma unroll
            for (int k = 0; k < 8; ++k)
                r[k] = (short)tile[(cb * 8 + k) * TPAD + ww];
            *(s16x8*)(Sp + ww * 64 + cb * 8) = r;
        }
    } else {
        const int p = blk - BATCH * HH;
        const float* wp = w + p * 576;
        float s = 0.f;
        for (int i = tid; i < 576; i += 256) s += fabsf(wp[i]);
#pragma unroll
        for (int off = 32; off > 0; off >>= 1) s += __shfl_down(s, off);
        const int lane = tid & 63, wv = tid >> 6;
        if (lane == 0) red[wv] = s;
        __syncthreads();
        if (tid == 0) {
            float scale = (red[0] + red[1] + red[2] + red[3]) * (1.0f / 576.0f);
            float inv = gamma[p] * rsqrtf(rvar[p] + 1e-5f);
            consts[p]       = scale * inv;                       // A_mul
            consts[64 + p]  = beta[p] - rmean[p] * inv + bias1[p]; // B_add
            consts[128 + p] = alpha[p];
            consts[192 + p] = bias2[p];
        }
        // wsgn[tap][p][c] = sign(w[p][c][tap])
        for (int i = tid; i < 576; i += 256) {
            int c = i / 9, tap = i - c * 9;
            wsgn[((tap << 6) + p) * 64 + c] = sign_bf16(wp[i]);
        }
    }
}

// Kernel 2: implicit-GEMM binary conv, fused BN/residual/PReLU epilogue.
// 512 threads (8 waves), each wave: 32 positions x 64 channels.
// Block = 256 positions; grid = 784. LDS 73.7KB -> 2 blocks/CU -> 4 waves/SIMD.
__global__ __launch_bounds__(512, 4)
void conv_kernel(const ushort* __restrict__ S,
                 const ushort* __restrict__ wsgn,
                 const float* __restrict__ x,
                 const float* __restrict__ consts,
                 float* __restrict__ out) {
    __shared__ __align__(16) ushort bsm[9 * 64 * 64]; // 73,728 B

    // Stage all 9 taps of weight signs with XOR-chunk swizzle:
    // content chunk c8 (8ch=16B) stored at chunk (c8 ^ (p&7)).
    for (int i = threadIdx.x; i < 9 * 64 * 8; i += 512) {
        int c8 = i & 7;
        int p = (i >> 3) & 63;
        int tap = i >> 9;
        uint4 v = *(const uint4*)(wsgn + (((tap << 6) + p) << 6) + (c8 << 3));
        *(uint4*)(bsm + (((tap << 6) + p) << 6) + ((c8 ^ (p & 7)) << 3)) = v;
    }
    __syncthreads();

    const int lane = threadIdx.x & 63;
    const int wv = threadIdx.x >> 6;        // 0..7
    const int mbase = (blockIdx.x << 8) + (wv << 5);
    const int lr = lane & 15;   // A-row (position) / D-col (channel) index
    const int cg = lane >> 4;   // k-group 0..3

    int bb[2], hb[2], wb[2];
#pragma unroll
    for (int mt = 0; mt < 2; ++mt) {
        int m = mbase + (mt << 4) + lr;
        bb[mt] = m / HW;
        int r = m - bb[mt] * HW;
        hb[mt] = r / WW;
        wb[mt] = r - hb[mt] * WW;
    }

    f32x4 acc[2][4] = {};

#pragma unroll
    for (int tap = 0; tap < 9; ++tap) {
        const int dh = tap / 3 - 1, dw = tap % 3 - 1;
        s16x8 a[2][2];
#pragma unroll
        for (int mt = 0; mt < 2; ++mt) {
            int hh = hb[mt] + dh, ww = wb[mt] + dw;
            bool valid = ((unsigned)hh < (unsigned)HH) & ((unsigned)ww < (unsigned)WW);
            if (valid) {
                const ushort* sp = S + ((((size_t)bb[mt] * HH + hh) * WW + ww) << 6) + (cg << 3);
                a[mt][0] = *(const s16x8*)(sp);
                a[mt][1] = *(const s16x8*)(sp + 32);
            } else {
                a[mt][0] = s16x8{};
                a[mt][1] = s16x8{};
            }
        }
#pragma unroll
        for (int nt = 0; nt < 4; ++nt) {
            const int p = (nt << 4) + lr;
            const ushort* bp = bsm + (((tap << 6) + p) << 6);
            s16x8 b0 = *(const s16x8*)(bp + ((cg ^ (p & 7)) << 3));
            s16x8 b1 = *(const s16x8*)(bp + (((4 + cg) ^ (p & 7)) << 3));
#pragma unroll
            for (int mt = 0; mt < 2; ++mt) {
                acc[mt][nt] = __builtin_amdgcn_mfma_f32_16x16x32_bf16(
                    as_bf(a[mt][0]), as_bf(b0), acc[mt][nt], 0, 0, 0);
                acc[mt][nt] = __builtin_amdgcn_mfma_f32_16x16x32_bf16(
                    as_bf(a[mt][1]), as_bf(b1), acc[mt][nt], 0, 0, 0);
            }
        }
    }

    // Epilogue: out = PReLU(acc*A_mul + B_add + residual) + bias2
#pragma unroll
    for (int mt = 0; mt < 2; ++mt) {
        int m0 = mbase + (mt << 4) + (cg << 2);  // 4 consecutive w (aligned)
        int b = m0 / HW;
        int r = m0 - b * HW;
        int h = r / WW;
        int w0 = r - h * WW;
#pragma unroll
        for (int nt = 0; nt < 4; ++nt) {
            int p = (nt << 4) + lr;
            float am = consts[p];
            float bd = consts[64 + p];
            float al = consts[128 + p];
            float b2 = consts[192 + p];
            size_t off = ((((size_t)b << 6) + p) * HH + h) * WW + w0;
            float4 res = *(const float4*)(x + off);
            float4 o;
            const float* accp = (const float*)&acc[mt][nt];
            const float* rp = (const float*)&res;
            float* op = (float*)&o;
#pragma unroll
            for (int rr = 0; rr < 4; ++rr) {
                float v = accp[rr] * am + bd + rp[rr];
                v = v >= 0.f ? v : al * v;
                op[rr] = v + b2;
            }
            *(float4*)(out + off) = o;
        }
    }
}

extern "C" void kernel_launch(void* const* d_in, const int* in_sizes, int n_in,
                              void* d_out, int out_size, void* d_ws, size_t ws_size,
                              hipStream_t stream) {
    const float* x     = (const float*)d_in[0];
    const float* bias0 = (const float*)d_in[1];
    const float* w     = (const float*)d_in[2];
    const float* gamma = (const float*)d_in[3];
    const float* beta  = (const float*)d_in[4];
    const float* rmean = (const float*)d_in[5];
    const float* rvar  = (const float*)d_in[6];
    const float* bias1 = (const float*)d_in[7];
    const float* alpha = (const float*)d_in[8];
    const float* bias2 = (const float*)d_in[9];
    float* out = (float*)d_out;

    char* ws = (char*)d_ws;
    float* consts = (float*)ws;                       // 256 f32 = 1 KB
    ushort* wsgn  = (ushort*)(ws + 1024);             // 73,728 B
    ushort* S     = (ushort*)(ws + 1024 + 73728);     // 25,690,112 B

    sign_prep_kernel<<<BATCH * HH + 64, 256, 0, stream>>>(
        x, bias0, w, gamma, beta, rmean, rvar, bias1, alpha, bias2, S, wsgn, consts);

    conv_kernel<<<M_TOT / 256, 512, 0, stream>>>(S, wsgn, x, consts, out);
}